// Round 1
// 409.427 us; speedup vs baseline: 1.0395x; 1.0395x over previous
//
#include <hip/hip_runtime.h>

// Sizes fixed by the problem.
#define TT 1653          // T
#define DD 512           // D
#define BB 2             // B
#define DE 64            // D/E
#define BEH 16           // B*E
#define TTILES 26        // ceil(T/64)
#define TPAD 1664        // T padded to multiple of 64
#define SQN 26           // ovt4 s-tiles (TPAD/64)
#define NJC 4            // ovt4 j-split
#define MPSTRIDE TPAD    // Mpart row stride (floats)

typedef __attribute__((ext_vector_type(8))) short bf16x8;   // 8 bf16 (4 VGPRs)
typedef __attribute__((ext_vector_type(4))) float f32x4;
typedef short bf16x8u __attribute__((ext_vector_type(8), aligned(4)));
typedef float f32x4u  __attribute__((ext_vector_type(4), aligned(4)));  // O rows are only 4B-aligned (TT odd)

__device__ __forceinline__ short f2bf(float f) {
    union { float f; unsigned u; } v; v.f = f;
    unsigned r = v.u + 0x7fffu + ((v.u >> 16) & 1u);   // RNE
    return (short)(r >> 16);
}
__device__ __forceinline__ unsigned pack2(float a, float b) {
    return (unsigned)(unsigned short)f2bf(a) | ((unsigned)(unsigned short)f2bf(b) << 16);
}
__device__ __forceinline__ float bf2f(short s) {
    union { unsigned u; float f; } v; v.u = ((unsigned)(unsigned short)s) << 16;
    return v.f;
}
__device__ __forceinline__ bf16x8 ld_frag4(const short* p) {   // 4B-aligned LDS frag load
    bf16x8u v = *(const bf16x8u*)p;
    return (bf16x8)v;
}

// ---------------------------------------------------------------------------
// Kernel 0: punish matrix -> bf16 [T][TPAD], zero pad cols.
// ---------------------------------------------------------------------------
__global__ __launch_bounds__(256) void convp2_kernel(
    const float* __restrict__ P, short* __restrict__ Pbf)
{
    const int g = blockIdx.x * 256 + threadIdx.x;
    const int NG4 = TPAD / 4;                       // 416
    if (g >= TT * NG4) return;
    const int r = g / NG4, c4 = (g - r * NG4) * 4;
    float p0 = 0.f, p1 = 0.f, p2 = 0.f, p3 = 0.f;
    const float* prow = P + (size_t)r * TT;
    if (c4 + 0 < TT) p0 = prow[c4 + 0];
    if (c4 + 1 < TT) p1 = prow[c4 + 1];
    if (c4 + 2 < TT) p2 = prow[c4 + 2];
    if (c4 + 3 < TT) p3 = prow[c4 + 3];
    uint2 o; o.x = pack2(p0, p1); o.y = pack2(p2, p3);
    *(uint2*)(Pbf + (size_t)r * TPAD + c4) = o;
}

// ---------------------------------------------------------------------------
// Kernel 1 (MFMA): projections Q/K/V in [B, D, T] scramble layout, bf16 out.
//   Y[b,d,t] = sum_k W[d,k] X[b,t,k] (+bias, sigmoid for Q/K)
// ---------------------------------------------------------------------------
__global__ __launch_bounds__(256) void proj2_kernel(
    const float* __restrict__ X,
    const float* __restrict__ W0, const float* __restrict__ b0,
    const float* __restrict__ W1, const float* __restrict__ b1,
    const float* __restrict__ W2, const float* __restrict__ b2,
    short* __restrict__ Y0, short* __restrict__ Y1, short* __restrict__ Y2)
{
    __shared__ short Wsh[64][72];  // [d][k] bf16
    __shared__ short Xs[64][72];   // [t][k] bf16

    const int tt = blockIdx.x, dt = blockIdx.y, z = blockIdx.z;
    const int b = z / 3, which = z % 3;
    const float* W    = (which == 0) ? W0 : (which == 1) ? W1 : W2;
    const float* bias = (which == 0) ? b0 : (which == 1) ? b1 : b2;
    short* Y          = (which == 0) ? Y0 : (which == 1) ? Y1 : Y2;

    const int t0 = tt * 64, d0 = dt * 64;
    const float* Xb = X + (size_t)b * TT * DD;

    const int tid  = threadIdx.x;
    const int wave = tid >> 6, lane = tid & 63;
    const int quad = lane >> 4, l16 = lane & 15;
    const int srow = tid >> 2, scg = (tid & 3) * 16;

    f32x4 acc[4];
    #pragma unroll
    for (int i = 0; i < 4; ++i) acc[i] = (f32x4){0.f, 0.f, 0.f, 0.f};

    for (int k0 = 0; k0 < DD; k0 += 64) {
        {
            const float* wrow = W + (size_t)(d0 + srow) * DD + k0 + scg;
            float4 w0 = *(const float4*)(wrow);
            float4 w1 = *(const float4*)(wrow + 4);
            float4 w2 = *(const float4*)(wrow + 8);
            float4 w3 = *(const float4*)(wrow + 12);
            uint4 pw0, pw1;
            pw0.x = pack2(w0.x, w0.y); pw0.y = pack2(w0.z, w0.w);
            pw0.z = pack2(w1.x, w1.y); pw0.w = pack2(w1.z, w1.w);
            pw1.x = pack2(w2.x, w2.y); pw1.y = pack2(w2.z, w2.w);
            pw1.z = pack2(w3.x, w3.y); pw1.w = pack2(w3.z, w3.w);

            const int t = t0 + srow;
            float4 x0 = make_float4(0.f,0.f,0.f,0.f), x1 = x0, x2 = x0, x3 = x0;
            if (t < TT) {
                const float* xrow = Xb + (size_t)t * DD + k0 + scg;
                x0 = *(const float4*)(xrow);
                x1 = *(const float4*)(xrow + 4);
                x2 = *(const float4*)(xrow + 8);
                x3 = *(const float4*)(xrow + 12);
            }
            uint4 px0, px1;
            px0.x = pack2(x0.x, x0.y); px0.y = pack2(x0.z, x0.w);
            px0.z = pack2(x1.x, x1.y); px0.w = pack2(x1.z, x1.w);
            px1.x = pack2(x2.x, x2.y); px1.y = pack2(x2.z, x2.w);
            px1.z = pack2(x3.x, x3.y); px1.w = pack2(x3.z, x3.w);

            __syncthreads();
            *(uint4*)&Wsh[srow][scg]     = pw0;
            *(uint4*)&Wsh[srow][scg + 8] = pw1;
            *(uint4*)&Xs[srow][scg]      = px0;
            *(uint4*)&Xs[srow][scg + 8]  = px1;
        }
        __syncthreads();

        #pragma unroll
        for (int ks = 0; ks < 2; ++ks) {
            bf16x8 a = *(const bf16x8*)&Wsh[wave * 16 + l16][ks * 32 + quad * 8];
            #pragma unroll
            for (int nt = 0; nt < 4; ++nt) {
                bf16x8 bb = *(const bf16x8*)&Xs[nt * 16 + l16][ks * 32 + quad * 8];
                acc[nt] = __builtin_amdgcn_mfma_f32_16x16x32_bf16(a, bb, acc[nt], 0, 0, 0);
            }
        }
    }

    #pragma unroll
    for (int nt = 0; nt < 4; ++nt) {
        const int t = t0 + nt * 16 + l16;
        if (t < TT) {
            #pragma unroll
            for (int r = 0; r < 4; ++r) {
                const int d = d0 + wave * 16 + quad * 4 + r;
                float v = acc[nt][r] + bias[d];
                if (which < 2) v = 1.2f / (1.0f + __expf(-1.6f * v));
                Y[((size_t)b * DD + d) * TT + t] = f2bf(v);
            }
        }
    }
}

// ---------------------------------------------------------------------------
// Kernel 2 (MFMA): partial Mt.  v4 — latency-oriented rewrite.
//   Mpart[jc][be][d][s] = sum_{j in chunk jc} V[j][d] * O[j][s]
//
// Theory (from r0 counters: MfmaUtil 2%, VALUBusy 12%, HBM 18%, Occ 31%):
// latency-starved, not throughput-bound. Changes vs ovt3:
//   - STILE 128 -> 64: grid (26,16,4)=1664 blocks, LDS 16.9 KB -> up to
//     8 resident blocks/CU (whole grid ~co-resident).
//   - O loads: global_load_dwordx4 per lane (2 rows x float4, packed to bf16
//     j-pairs in-register) instead of scalar dwords: 4x bytes per VMEM instr.
//   - T14 issue-early: tile t+1 global loads are issued right after tile t's
//     ds_writes; they complete under the MFMA phase + barriers.
// LDS row stride 66 shorts (33 dwords == 1 mod 32): transpose-pack writes
// stay <=2-way (free). Frag reads split to b32 (rows only 4B-aligned) --
// acceptable, kernel is nowhere near LDS-throughput-bound.
// OOB: row indices clamped (garbage * zero-padded V = 0); only sq==25 has a
// column overhang -> block-uniform predicated scalar slow path.
// ---------------------------------------------------------------------------
__global__ __launch_bounds__(256, 6) void ovt4_kernel(
    const float* __restrict__ orth, const short* __restrict__ Vb,
    float* __restrict__ Mpart)
{
    __shared__ short Os[64][66];  // [s_local][j_local] bf16
    __shared__ short Vs[64][66];  // [d][j_local] bf16

    const int sq = blockIdx.x, be = blockIdx.y, jc = blockIdx.z;
    const int s0 = sq * 64;
    const int jt0 = (jc < 2) ? jc * 7 : 14 + (jc - 2) * 6;   // tiles {7,7,6,6}
    const int jtn = (jc < 2) ? 7 : 6;

    const float* O  = orth + (size_t)be * TT * TT;
    const short* Vh = Vb + (size_t)be * DE * TT;   // head block, scramble [j][64]

    const int tid  = threadIdx.x;
    const int wave = tid >> 6, lane = tid & 63;
    const int quad = lane >> 4, l16 = lane & 15;

    const int c4 = tid & 15;          // col group: local cols 4*c4 .. 4*c4+3
    const int pr = tid >> 4;          // row-pair base 0..15 (pairs pr, pr+16)
    const int ca = s0 + 4 * c4;       // global col base
    const bool fastS = (s0 + 64 <= TT);   // all 64 cols in range (sq <= 24)

    f32x4 acc[4];
    #pragma unroll
    for (int i = 0; i < 4; ++i) acc[i] = (f32x4){0.f, 0.f, 0.f, 0.f};

    // staging registers (one tile in flight; compiler SSA double-buffers)
    f32x4u o0a, o0b, o1a, o1b;        // step0 rows (j0+2pr, +1); step1 rows (+32)
    uint2  v0a, v0b, v1a, v1b;

    auto stage_load = [&](int j0) {
        const int jA0 = j0 + 2 * pr;
        const int jA1 = jA0 + 32;
        const int r0  = min(jA0,     TT - 1);   // clamp: garbage rows hit V==0
        const int r0b = min(jA0 + 1, TT - 1);
        const int r1  = min(jA1,     TT - 1);
        const int r1b = min(jA1 + 1, TT - 1);
        if (fastS) {
            o0a = *(const f32x4u*)(O + (size_t)r0  * TT + ca);
            o0b = *(const f32x4u*)(O + (size_t)r0b * TT + ca);
            o1a = *(const f32x4u*)(O + (size_t)r1  * TT + ca);
            o1b = *(const f32x4u*)(O + (size_t)r1b * TT + ca);
        } else {
            #pragma unroll
            for (int i = 0; i < 4; ++i) {
                const int col = ca + i;
                const bool cv = (col < TT);
                o0a[i] = cv ? O[(size_t)r0  * TT + col] : 0.f;
                o0b[i] = cv ? O[(size_t)r0b * TT + col] : 0.f;
                o1a[i] = cv ? O[(size_t)r1  * TT + col] : 0.f;
                o1b[i] = cv ? O[(size_t)r1b * TT + col] : 0.f;
            }
        }
        const uint2 z = make_uint2(0u, 0u);
        v0a = (jA0     < TT) ? *(const uint2*)(Vh + (size_t)jA0       * DE + 4 * c4) : z;
        v0b = (jA0 + 1 < TT) ? *(const uint2*)(Vh + (size_t)(jA0 + 1) * DE + 4 * c4) : z;
        v1a = (jA1     < TT) ? *(const uint2*)(Vh + (size_t)jA1       * DE + 4 * c4) : z;
        v1b = (jA1 + 1 < TT) ? *(const uint2*)(Vh + (size_t)(jA1 + 1) * DE + 4 * c4) : z;
    };

    auto lds_write = [&]() {
        // O transpose-pack: Os[s][j-pair] dwords. Banks: (4*c4+i)*33 + p over
        // 64 lanes covers 0..63 mod 32 -> exactly 2-way (free).
        #pragma unroll
        for (int i = 0; i < 4; ++i) {
            *(unsigned*)&Os[4 * c4 + i][2 * pr]      = pack2(o0a[i], o0b[i]);
            *(unsigned*)&Os[4 * c4 + i][2 * pr + 32] = pack2(o1a[i], o1b[i]);
        }
        // V transpose (already bf16: bit-repack)
        *(unsigned*)&Vs[4 * c4 + 0][2 * pr]      = (v0a.x & 0xffffu) | (v0b.x << 16);
        *(unsigned*)&Vs[4 * c4 + 1][2 * pr]      = (v0a.x >> 16)     | (v0b.x & 0xffff0000u);
        *(unsigned*)&Vs[4 * c4 + 2][2 * pr]      = (v0a.y & 0xffffu) | (v0b.y << 16);
        *(unsigned*)&Vs[4 * c4 + 3][2 * pr]      = (v0a.y >> 16)     | (v0b.y & 0xffff0000u);
        *(unsigned*)&Vs[4 * c4 + 0][2 * pr + 32] = (v1a.x & 0xffffu) | (v1b.x << 16);
        *(unsigned*)&Vs[4 * c4 + 1][2 * pr + 32] = (v1a.x >> 16)     | (v1b.x & 0xffff0000u);
        *(unsigned*)&Vs[4 * c4 + 2][2 * pr + 32] = (v1a.y & 0xffffu) | (v1b.y << 16);
        *(unsigned*)&Vs[4 * c4 + 3][2 * pr + 32] = (v1a.y >> 16)     | (v1b.y & 0xffff0000u);
    };

    stage_load(jt0 * 64);
    for (int t = 0; t < jtn; ++t) {
        if (t) __syncthreads();           // prev MFMA done reading LDS
        lds_write();                      // waits vmcnt for tile t regs
        if (t + 1 < jtn) stage_load((jt0 + t + 1) * 64);   // issue-early (T14)
        __syncthreads();
        // wave owns s-strip [wave*16, +16), all 64 d
        #pragma unroll
        for (int ks = 0; ks < 2; ++ks) {
            bf16x8 bb = ld_frag4(&Os[wave * 16 + l16][ks * 32 + quad * 8]);
            #pragma unroll
            for (int i = 0; i < 4; ++i) {
                bf16x8 a = ld_frag4(&Vs[i * 16 + l16][ks * 32 + quad * 8]);
                acc[i] = __builtin_amdgcn_mfma_f32_16x16x32_bf16(a, bb, acc[i], 0, 0, 0);
            }
        }
    }

    // epilogue: d = i*16+quad*4+r, s = s0 + wave*16 + l16 (always < TPAD)
    float* Mp = Mpart + (size_t)(jc * BEH + be) * DE * MPSTRIDE;
    const int s = s0 + wave * 16 + l16;
    #pragma unroll
    for (int i = 0; i < 4; ++i) {
        #pragma unroll
        for (int r = 0; r < 4; ++r) {
            const int d = i * 16 + quad * 4 + r;
            Mp[(size_t)d * MPSTRIDE + s] = acc[i][r];
        }
    }
}

// ---------------------------------------------------------------------------
// Kernel 2b: reduce the 4 j-chunk partials -> bf16 Mt[be][d][TPAD].
// ---------------------------------------------------------------------------
__global__ __launch_bounds__(256) void mreduce_kernel(
    const float* __restrict__ Mpart, short* __restrict__ Mt)
{
    const int g = blockIdx.x * 256 + threadIdx.x;
    const int NG = TPAD / 4;                        // 416
    if (g >= BEH * DE * NG) return;
    const int bd = g / NG;
    const int s4 = (g - bd * NG) * 4;

    const size_t jstride = (size_t)BEH * DE * MPSTRIDE;
    const float* p = Mpart + (size_t)bd * MPSTRIDE + s4;
    float4 a0 = *(const float4*)(p);
    float4 a1 = *(const float4*)(p + jstride);
    float4 a2 = *(const float4*)(p + 2 * jstride);
    float4 a3 = *(const float4*)(p + 3 * jstride);
    float s0 = a0.x + a1.x + a2.x + a3.x;
    float s1 = a0.y + a1.y + a2.y + a3.y;
    float s2 = a0.z + a1.z + a2.z + a3.z;
    float s3 = a0.w + a1.w + a2.w + a3.w;

    uint2 o;
    o.x = pack2(s0, s1);
    o.y = pack2(s2, s3);
    *(uint2*)(Mt + (size_t)bd * TPAD + s4) = o;
}

// ---------------------------------------------------------------------------
// Kernel 3 (MFMA): fused attention, P in bf16 (exact shift to fp32 on use).
// LDS = 5 x 9216 = 46 KB -> 3 blocks/CU.
// ---------------------------------------------------------------------------
__global__ __launch_bounds__(256) void attn2_kernel(
    const short* __restrict__ Qb, const short* __restrict__ Kb,
    const short* __restrict__ Mt, const short* __restrict__ Pbf,
    float* __restrict__ Hbuf)
{
    __shared__ short Qs[64][72];  // [i][d]
    __shared__ short Ks[64][72];  // [s][d]
    __shared__ short Ms[64][72];  // [d][s]
    __shared__ short Wl[64][72];  // [i][s]
    __shared__ short Ps[64][72];  // [i][s] bf16 punish tile

    const int it = blockIdx.x, be = blockIdx.y;
    const int b = be >> 3, e = be & 7;
    const int i0 = it * 64;
    const short* Qh = Qb + (size_t)be * DE * TT;
    const short* Kh = Kb + (size_t)be * DE * TT;
    const short* Mh = Mt + (size_t)be * DE * TPAD;

    const int tid  = threadIdx.x;
    const int wave = tid >> 6, lane = tid & 63;
    const int quad = lane >> 4, l16 = lane & 15;

    const float invs = 0.024598297f;  // 1/sqrt(1653)

    const int srow = tid >> 2, scg = (tid & 3) * 16;

    {
        const int gi = i0 + srow;
        uint4 z = make_uint4(0u, 0u, 0u, 0u);
        uint4 v0 = z, v1 = z;
        if (gi < TT) {
            v0 = *(const uint4*)(Qh + (size_t)gi * DE + scg);
            v1 = *(const uint4*)(Qh + (size_t)gi * DE + scg + 8);
        }
        *(uint4*)&Qs[srow][scg]     = v0;
        *(uint4*)&Qs[srow][scg + 8] = v1;
    }

    f32x4 out[4];
    #pragma unroll
    for (int i = 0; i < 4; ++i) out[i] = (f32x4){0.f, 0.f, 0.f, 0.f};

    for (int s0 = 0; s0 < TT; s0 += 64) {
        {
            const int gs = s0 + srow;
            uint4 z = make_uint4(0u, 0u, 0u, 0u);
            uint4 k0 = z, k1 = z;
            if (gs < TT) {
                k0 = *(const uint4*)(Kh + (size_t)gs * DE + scg);
                k1 = *(const uint4*)(Kh + (size_t)gs * DE + scg + 8);
            }
            *(uint4*)&Ks[srow][scg]     = k0;
            *(uint4*)&Ks[srow][scg + 8] = k1;

            uint4 m0 = *(const uint4*)(Mh + (size_t)srow * TPAD + s0 + scg);
            uint4 m1 = *(const uint4*)(Mh + (size_t)srow * TPAD + s0 + scg + 8);
            *(uint4*)&Ms[srow][scg]     = m0;
            *(uint4*)&Ms[srow][scg + 8] = m1;

            const int gi = i0 + srow;
            uint4 p0 = z, p1 = z;
            if (gi < TT) {
                p0 = *(const uint4*)(Pbf + (size_t)gi * TPAD + s0 + scg);
                p1 = *(const uint4*)(Pbf + (size_t)gi * TPAD + s0 + scg + 8);
            }
            *(uint4*)&Ps[srow][scg]     = p0;
            *(uint4*)&Ps[srow][scg + 8] = p1;
        }
        __syncthreads();

        f32x4 w[4];
        #pragma unroll
        for (int i = 0; i < 4; ++i) w[i] = (f32x4){0.f, 0.f, 0.f, 0.f};
        #pragma unroll
        for (int ks = 0; ks < 2; ++ks) {
            bf16x8 a = *(const bf16x8*)&Qs[wave * 16 + l16][ks * 32 + quad * 8];
            #pragma unroll
            for (int stile = 0; stile < 4; ++stile) {
                bf16x8 bb = *(const bf16x8*)&Ks[stile * 16 + l16][ks * 32 + quad * 8];
                w[stile] = __builtin_amdgcn_mfma_f32_16x16x32_bf16(a, bb, w[stile], 0, 0, 0);
            }
        }

        #pragma unroll
        for (int stile = 0; stile < 4; ++stile) {
            const int sl = stile * 16 + l16;
            #pragma unroll
            for (int r = 0; r < 4; ++r) {
                const int il = wave * 16 + quad * 4 + r;
                float v = w[stile][r] * invs * bf2f(Ps[il][sl]);
                Wl[il][sl] = f2bf(v);
            }
        }

        #pragma unroll
        for (int ks = 0; ks < 2; ++ks) {
            bf16x8 a = *(const bf16x8*)&Wl[wave * 16 + l16][ks * 32 + quad * 8];
            #pragma unroll
            for (int dt = 0; dt < 4; ++dt) {
                bf16x8 bb = *(const bf16x8*)&Ms[dt * 16 + l16][ks * 32 + quad * 8];
                out[dt] = __builtin_amdgcn_mfma_f32_16x16x32_bf16(a, bb, out[dt], 0, 0, 0);
            }
        }
        __syncthreads();
    }

    #pragma unroll
    for (int dt = 0; dt < 4; ++dt) {
        const int d = dt * 16 + l16;
        #pragma unroll
        for (int r = 0; r < 4; ++r) {
            const int gi = i0 + wave * 16 + quad * 4 + r;
            if (gi < TT)
                Hbuf[((size_t)b * TT + gi) * DD + e * 64 + d] = out[dt][r];
        }
    }
}

// ---------------------------------------------------------------------------
// Kernel 4: final projection (fp32 SGEMM, precision anchor for the output).
// ---------------------------------------------------------------------------
__global__ __launch_bounds__(256) void oproj_kernel(
    const float* __restrict__ H, const float* __restrict__ Wo,
    const float* __restrict__ bo, float* __restrict__ out)
{
    __shared__ float Hs[16][68];
    __shared__ float Ns[16][68];

    const int tt = blockIdx.x, nt = blockIdx.y, b = blockIdx.z;
    const int t0 = tt * 64, n0 = nt * 64;
    const float* Hb = H + (size_t)b * TT * DD;

    const int tid = threadIdx.x;
    const int tx = tid & 15, ty = tid >> 4;
    const int lrow = tid >> 2, lq = tid & 3;
    const int trow = t0 + lrow;

    float acc[4][4] = {};

    for (int k0 = 0; k0 < DD; k0 += 16) {
        float4 hv = make_float4(0.f, 0.f, 0.f, 0.f);
        if (trow < TT)
            hv = *(const float4*)(Hb + (size_t)trow * DD + k0 + lq*4);
        float4 wv = *(const float4*)(Wo + (size_t)(n0 + lrow) * DD + k0 + lq*4);
        __syncthreads();
        Hs[lq*4+0][lrow] = hv.x; Hs[lq*4+1][lrow] = hv.y;
        Hs[lq*4+2][lrow] = hv.z; Hs[lq*4+3][lrow] = hv.w;
        Ns[lq*4+0][lrow] = wv.x; Ns[lq*4+1][lrow] = wv.y;
        Ns[lq*4+2][lrow] = wv.z; Ns[lq*4+3][lrow] = wv.w;
        __syncthreads();
        #pragma unroll
        for (int k = 0; k < 16; ++k) {
            float4 a4 = *(const float4*)(&Hs[k][ty*4]);
            float4 c4 = *(const float4*)(&Ns[k][tx*4]);
            float a[4] = {a4.x, a4.y, a4.z, a4.w};
            float c[4] = {c4.x, c4.y, c4.z, c4.w};
            #pragma unroll
            for (int i = 0; i < 4; ++i)
                #pragma unroll
                for (int j = 0; j < 4; ++j)
                    acc[i][j] = fmaf(a[i], c[j], acc[i][j]);
        }
        __syncthreads();
    }

    #pragma unroll
    for (int i = 0; i < 4; ++i) {
        const int t = t0 + ty*4 + i;
        if (t < TT) {
            float4 v;
            v.x = acc[i][0] + bo[n0 + tx*4 + 0];
            v.y = acc[i][1] + bo[n0 + tx*4 + 1];
            v.z = acc[i][2] + bo[n0 + tx*4 + 2];
            v.w = acc[i][3] + bo[n0 + tx*4 + 3];
            *(float4*)(out + ((size_t)b * TT + t) * DD + n0 + tx*4) = v;
        }
    }
}

// ---------------------------------------------------------------------------
extern "C" void kernel_launch(void* const* d_in, const int* in_sizes, int n_in,
                              void* d_out, int out_size, void* d_ws, size_t ws_size,
                              hipStream_t stream)
{
    (void)in_sizes; (void)n_in; (void)out_size; (void)ws_size;

    const float* X    = (const float*)d_in[0];
    const float* Wq   = (const float*)d_in[1];
    const float* bq   = (const float*)d_in[2];
    const float* Wk   = (const float*)d_in[3];
    const float* bk   = (const float*)d_in[4];
    const float* Wv   = (const float*)d_in[5];
    const float* bv   = (const float*)d_in[6];
    const float* Wo   = (const float*)d_in[7];
    const float* bo   = (const float*)d_in[8];
    const float* P    = (const float*)d_in[9];
    const float* orth = (const float*)d_in[10];
    float* out = (float*)d_out;

    // Workspace layout (~46.3 MB):
    //   Qb/Kb/Vb bf16 [B*D*T]        3 x 3,385,344 B
    //   Mtb      bf16 [BE*64*TPAD]       3,407,872 B
    //   Pbf      bf16 [T*TPAD]           5,501,184 B
    //   Mpart    fp32 [4][BE*64][TPAD]  27,262,976 B  (dead after mreduce)
    //   Hbuf     fp32 [B*T*D] -- ALIASES Mpart (written by attn after mreduce)
    char* ws = (char*)d_ws;
    const size_t SZH = (size_t)BB * DD * TT * sizeof(short);
    short* Qb  = (short*)(ws);
    short* Kb  = (short*)(ws + SZH);
    short* Vb  = (short*)(ws + 2 * SZH);
    short* Mtb = (short*)(ws + 3 * SZH);
    short* Pbf = (short*)(ws + 3 * SZH + (size_t)BEH * DE * TPAD * sizeof(short));
    char*  after_p = ws + 3 * SZH + (size_t)BEH * DE * TPAD * sizeof(short)
                        + (size_t)TT * TPAD * sizeof(short);
    float* Mpart = (float*)after_p;
    float* Hbuf  = (float*)after_p;   // alias: Mpart dead before attn runs

    dim3 blk(256);

    convp2_kernel<<<dim3((TT * (TPAD / 4) + 255) / 256), blk, 0, stream>>>(P, Pbf);

    dim3 g1(TTILES, DD / 64, BB * 3);
    proj2_kernel<<<g1, blk, 0, stream>>>(X, Wq, bq, Wk, bk, Wv, bv, Qb, Kb, Vb);

    dim3 g2(SQN, BEH, NJC);
    ovt4_kernel<<<g2, blk, 0, stream>>>(orth, Vb, Mpart);

    dim3 gr((BEH * DE * (TPAD / 4) + 255) / 256);
    mreduce_kernel<<<gr, blk, 0, stream>>>(Mpart, Mtb);

    dim3 g3(TTILES, BEH);
    attn2_kernel<<<g3, blk, 0, stream>>>(Qb, Kb, Mtb, Pbf, Hbuf);

    dim3 g4(TTILES, DD / 64, BB);
    oproj_kernel<<<g4, blk, 0, stream>>>(Hbuf, Wo, bo, out);
}

// Round 2
// 407.999 us; speedup vs baseline: 1.0432x; 1.0035x over previous
//
#include <hip/hip_runtime.h>

// Sizes fixed by the problem.
#define TT 1653          // T
#define DD 512           // D
#define BB 2             // B
#define DE 64            // D/E
#define BEH 16           // B*E
#define TTILES 26        // ceil(T/64)
#define TPAD 1664        // T padded to multiple of 64
#define SQN 26           // ovt5 s-tiles (TPAD/64)
#define NJC 4            // ovt5 j-split
#define MPSTRIDE TPAD    // Mpart row stride (floats)

typedef __attribute__((ext_vector_type(8))) short bf16x8;   // 8 bf16 (4 VGPRs)
typedef __attribute__((ext_vector_type(4))) float f32x4;
typedef float f32x4u  __attribute__((ext_vector_type(4), aligned(4)));  // O rows only 4B-aligned (TT odd)

__device__ __forceinline__ short f2bf(float f) {
    union { float f; unsigned u; } v; v.f = f;
    unsigned r = v.u + 0x7fffu + ((v.u >> 16) & 1u);   // RNE
    return (short)(r >> 16);
}
__device__ __forceinline__ unsigned pack2(float a, float b) {
    return (unsigned)(unsigned short)f2bf(a) | ((unsigned)(unsigned short)f2bf(b) << 16);
}
__device__ __forceinline__ float bf2f(short s) {
    union { unsigned u; float f; } v; v.u = ((unsigned)(unsigned short)s) << 16;
    return v.f;
}

// ---------------------------------------------------------------------------
// Kernel 0: punish matrix -> bf16 [T][TPAD], zero pad cols.
// ---------------------------------------------------------------------------
__global__ __launch_bounds__(256) void convp2_kernel(
    const float* __restrict__ P, short* __restrict__ Pbf)
{
    const int g = blockIdx.x * 256 + threadIdx.x;
    const int NG4 = TPAD / 4;                       // 416
    if (g >= TT * NG4) return;
    const int r = g / NG4, c4 = (g - r * NG4) * 4;
    float p0 = 0.f, p1 = 0.f, p2 = 0.f, p3 = 0.f;
    const float* prow = P + (size_t)r * TT;
    if (c4 + 0 < TT) p0 = prow[c4 + 0];
    if (c4 + 1 < TT) p1 = prow[c4 + 1];
    if (c4 + 2 < TT) p2 = prow[c4 + 2];
    if (c4 + 3 < TT) p3 = prow[c4 + 3];
    uint2 o; o.x = pack2(p0, p1); o.y = pack2(p2, p3);
    *(uint2*)(Pbf + (size_t)r * TPAD + c4) = o;
}

// ---------------------------------------------------------------------------
// Kernel 1 (MFMA): projections Q/K/V in [B, D, T] scramble layout, bf16 out.
//   Y[b,d,t] = sum_k W[d,k] X[b,t,k] (+bias, sigmoid for Q/K)
// v3: 1-deep issue-early staging (loads for k0+64 issued before compute of k0).
// ---------------------------------------------------------------------------
__global__ __launch_bounds__(256) void proj3_kernel(
    const float* __restrict__ X,
    const float* __restrict__ W0, const float* __restrict__ b0,
    const float* __restrict__ W1, const float* __restrict__ b1,
    const float* __restrict__ W2, const float* __restrict__ b2,
    short* __restrict__ Y0, short* __restrict__ Y1, short* __restrict__ Y2)
{
    __shared__ __align__(16) short Wsh[64][72];  // [d][k] bf16
    __shared__ __align__(16) short Xs[64][72];   // [t][k] bf16

    const int tt = blockIdx.x, dt = blockIdx.y, z = blockIdx.z;
    const int b = z / 3, which = z % 3;
    const float* W    = (which == 0) ? W0 : (which == 1) ? W1 : W2;
    const float* bias = (which == 0) ? b0 : (which == 1) ? b1 : b2;
    short* Y          = (which == 0) ? Y0 : (which == 1) ? Y1 : Y2;

    const int t0 = tt * 64, d0 = dt * 64;
    const float* Xb = X + (size_t)b * TT * DD;

    const int tid  = threadIdx.x;
    const int wave = tid >> 6, lane = tid & 63;
    const int quad = lane >> 4, l16 = lane & 15;
    const int srow = tid >> 2, scg = (tid & 3) * 16;

    f32x4 acc[4];
    #pragma unroll
    for (int i = 0; i < 4; ++i) acc[i] = (f32x4){0.f, 0.f, 0.f, 0.f};

    float4 w0, w1, w2, w3, x0, x1, x2, x3;

    auto stage = [&](int k0) {
        const float* wrow = W + (size_t)(d0 + srow) * DD + k0 + scg;
        w0 = *(const float4*)(wrow);
        w1 = *(const float4*)(wrow + 4);
        w2 = *(const float4*)(wrow + 8);
        w3 = *(const float4*)(wrow + 12);
        const int t = t0 + srow;
        x0 = make_float4(0.f,0.f,0.f,0.f); x1 = x0; x2 = x0; x3 = x0;
        if (t < TT) {
            const float* xrow = Xb + (size_t)t * DD + k0 + scg;
            x0 = *(const float4*)(xrow);
            x1 = *(const float4*)(xrow + 4);
            x2 = *(const float4*)(xrow + 8);
            x3 = *(const float4*)(xrow + 12);
        }
    };
    auto lds_write = [&]() {
        uint4 pw0, pw1, px0, px1;
        pw0.x = pack2(w0.x, w0.y); pw0.y = pack2(w0.z, w0.w);
        pw0.z = pack2(w1.x, w1.y); pw0.w = pack2(w1.z, w1.w);
        pw1.x = pack2(w2.x, w2.y); pw1.y = pack2(w2.z, w2.w);
        pw1.z = pack2(w3.x, w3.y); pw1.w = pack2(w3.z, w3.w);
        px0.x = pack2(x0.x, x0.y); px0.y = pack2(x0.z, x0.w);
        px0.z = pack2(x1.x, x1.y); px0.w = pack2(x1.z, x1.w);
        px1.x = pack2(x2.x, x2.y); px1.y = pack2(x2.z, x2.w);
        px1.z = pack2(x3.x, x3.y); px1.w = pack2(x3.z, x3.w);
        *(uint4*)&Wsh[srow][scg]     = pw0;
        *(uint4*)&Wsh[srow][scg + 8] = pw1;
        *(uint4*)&Xs[srow][scg]      = px0;
        *(uint4*)&Xs[srow][scg + 8]  = px1;
    };

    stage(0);
    for (int k0 = 0; k0 < DD; k0 += 64) {
        if (k0) __syncthreads();
        lds_write();
        if (k0 + 64 < DD) stage(k0 + 64);
        __syncthreads();

        #pragma unroll
        for (int ks = 0; ks < 2; ++ks) {
            bf16x8 a = *(const bf16x8*)&Wsh[wave * 16 + l16][ks * 32 + quad * 8];
            #pragma unroll
            for (int nt = 0; nt < 4; ++nt) {
                bf16x8 bb = *(const bf16x8*)&Xs[nt * 16 + l16][ks * 32 + quad * 8];
                acc[nt] = __builtin_amdgcn_mfma_f32_16x16x32_bf16(a, bb, acc[nt], 0, 0, 0);
            }
        }
    }

    #pragma unroll
    for (int nt = 0; nt < 4; ++nt) {
        const int t = t0 + nt * 16 + l16;
        if (t < TT) {
            #pragma unroll
            for (int r = 0; r < 4; ++r) {
                const int d = d0 + wave * 16 + quad * 4 + r;
                float v = acc[nt][r] + bias[d];
                if (which < 2) v = 1.2f / (1.0f + __expf(-1.6f * v));
                Y[((size_t)b * DD + d) * TT + t] = f2bf(v);
            }
        }
    }
}

// ---------------------------------------------------------------------------
// Kernel 2 (MFMA): partial Mt.  v5 — 2-deep pipeline + stride-72 LDS.
//   Mpart[jc][be][d][s] = sum_{j in chunk jc} V[j][d] * O[j][s]
//
// Post-mortem of ovt4 (88us, floor ~37): residual per-tile latency exposure
// (1-deep prefetch covers ~500cy of a ~900cy HBM latency) + 4B-aligned LDS
// frag reads splitting to ds_read_b32.
// Changes:
//   - Row stride 72 shorts (144B = 9x16B): bank-group of 16B unit u in row r
//     is 4*((r+u) mod 8) -> natural swizzle: conflict-free ds_read_b128 frags
//     AND (with lane map p=tid&15 over j-pairs, sc=tid>>4 over cols) 32-bank
//     2-way-free transpose dword writes.
//   - 2-deep register prefetch (two static stage sets, unroll-2 loop):
//     consume-to-issue distance = 2 iterations > HBM latency; compiler emits
//     counted vmcnt (newer set's 8 loads may stay outstanding).
// ---------------------------------------------------------------------------
struct OVStage {
    f32x4u o0a, o0b, o1a, o1b;    // O rows j0+2p, +1, +32, +33 ; cols 4sc..+3
    uint2  v0a, v0b, v1a, v1b;    // V same rows ; d cols 4sc..+3
};

__global__ __launch_bounds__(256, 4) void ovt5_kernel(
    const float* __restrict__ orth, const short* __restrict__ Vb,
    float* __restrict__ Mpart)
{
    __shared__ __align__(16) short Os[64][72];  // [s_local][j_local] bf16
    __shared__ __align__(16) short Vs[64][72];  // [d][j_local] bf16

    const int sq = blockIdx.x, be = blockIdx.y, jc = blockIdx.z;
    const int s0 = sq * 64;
    const int jt0 = (jc < 2) ? jc * 7 : 14 + (jc - 2) * 6;   // tiles {7,7,6,6}
    const int jtn = (jc < 2) ? 7 : 6;

    const float* O  = orth + (size_t)be * TT * TT;
    const short* Vh = Vb + (size_t)be * DE * TT;   // head block, scramble [j][64]

    const int tid  = threadIdx.x;
    const int wave = tid >> 6, lane = tid & 63;
    const int quad = lane >> 4, l16 = lane & 15;

    const int p  = tid & 15;          // j-pair index (pairs p and p+16)
    const int sc = tid >> 4;          // col group 0..15: local cols 4sc..4sc+3
    const int ca = s0 + 4 * sc;       // global col base
    const bool fastS = (s0 + 64 <= TT);   // all 64 cols in range (sq <= 24)

    f32x4 acc[4];
    #pragma unroll
    for (int i = 0; i < 4; ++i) acc[i] = (f32x4){0.f, 0.f, 0.f, 0.f};

    auto stage_load = [&](OVStage& S, int j0) {
        const int jA = j0 + 2 * p;
        const int r0  = min(jA,      TT - 1);   // clamp: garbage rows hit V==0
        const int r0b = min(jA + 1,  TT - 1);
        const int r1  = min(jA + 32, TT - 1);
        const int r1b = min(jA + 33, TT - 1);
        if (fastS) {
            S.o0a = *(const f32x4u*)(O + (size_t)r0  * TT + ca);
            S.o0b = *(const f32x4u*)(O + (size_t)r0b * TT + ca);
            S.o1a = *(const f32x4u*)(O + (size_t)r1  * TT + ca);
            S.o1b = *(const f32x4u*)(O + (size_t)r1b * TT + ca);
        } else {
            #pragma unroll
            for (int i = 0; i < 4; ++i) {
                const int col = ca + i;
                const bool cv = (col < TT);
                S.o0a[i] = cv ? O[(size_t)r0  * TT + col] : 0.f;
                S.o0b[i] = cv ? O[(size_t)r0b * TT + col] : 0.f;
                S.o1a[i] = cv ? O[(size_t)r1  * TT + col] : 0.f;
                S.o1b[i] = cv ? O[(size_t)r1b * TT + col] : 0.f;
            }
        }
        const uint2 z = make_uint2(0u, 0u);
        S.v0a = (jA      < TT) ? *(const uint2*)(Vh + (size_t)jA       * DE + 4 * sc) : z;
        S.v0b = (jA + 1  < TT) ? *(const uint2*)(Vh + (size_t)(jA + 1) * DE + 4 * sc) : z;
        S.v1a = (jA + 32 < TT) ? *(const uint2*)(Vh + (size_t)(jA + 32)* DE + 4 * sc) : z;
        S.v1b = (jA + 33 < TT) ? *(const uint2*)(Vh + (size_t)(jA + 33)* DE + 4 * sc) : z;
    };

    auto lds_write = [&](const OVStage& S) {
        // O transpose-pack: dword at Os[4sc+i][pair p (+16)]. Banks:
        // (16sc + 4i + p) mod 32 over the wave = {p+4i, p+16+4i} -> all 32,
        // exactly 2 lanes/bank (free).
        #pragma unroll
        for (int i = 0; i < 4; ++i) {
            *(unsigned*)&Os[4 * sc + i][2 * p]      = pack2(S.o0a[i], S.o0b[i]);
            *(unsigned*)&Os[4 * sc + i][2 * p + 32] = pack2(S.o1a[i], S.o1b[i]);
        }
        // V transpose (already bf16: bit-repack)
        *(unsigned*)&Vs[4 * sc + 0][2 * p]      = (S.v0a.x & 0xffffu) | (S.v0b.x << 16);
        *(unsigned*)&Vs[4 * sc + 1][2 * p]      = (S.v0a.x >> 16)     | (S.v0b.x & 0xffff0000u);
        *(unsigned*)&Vs[4 * sc + 2][2 * p]      = (S.v0a.y & 0xffffu) | (S.v0b.y << 16);
        *(unsigned*)&Vs[4 * sc + 3][2 * p]      = (S.v0a.y >> 16)     | (S.v0b.y & 0xffff0000u);
        *(unsigned*)&Vs[4 * sc + 0][2 * p + 32] = (S.v1a.x & 0xffffu) | (S.v1b.x << 16);
        *(unsigned*)&Vs[4 * sc + 1][2 * p + 32] = (S.v1a.x >> 16)     | (S.v1b.x & 0xffff0000u);
        *(unsigned*)&Vs[4 * sc + 2][2 * p + 32] = (S.v1a.y & 0xffffu) | (S.v1b.y << 16);
        *(unsigned*)&Vs[4 * sc + 3][2 * p + 32] = (S.v1a.y >> 16)     | (S.v1b.y & 0xffff0000u);
    };

    auto mfma_tile = [&]() {
        #pragma unroll
        for (int ks = 0; ks < 2; ++ks) {
            bf16x8 bb = *(const bf16x8*)&Os[wave * 16 + l16][ks * 32 + quad * 8];
            #pragma unroll
            for (int i = 0; i < 4; ++i) {
                bf16x8 a = *(const bf16x8*)&Vs[i * 16 + l16][ks * 32 + quad * 8];
                acc[i] = __builtin_amdgcn_mfma_f32_16x16x32_bf16(a, bb, acc[i], 0, 0, 0);
            }
        }
    };

    OVStage sA, sB;
    stage_load(sA, (jt0 + 0) * 64);
    if (jtn > 1) stage_load(sB, (jt0 + 1) * 64);

    for (int t = 0; t < jtn; t += 2) {
        if (t) __syncthreads();
        lds_write(sA);
        if (t + 2 < jtn) stage_load(sA, (jt0 + t + 2) * 64);
        __syncthreads();
        mfma_tile();
        if (t + 1 < jtn) {
            __syncthreads();
            lds_write(sB);
            if (t + 3 < jtn) stage_load(sB, (jt0 + t + 3) * 64);
            __syncthreads();
            mfma_tile();
        }
    }

    // epilogue: d = i*16+quad*4+r, s = s0 + wave*16 + l16 (always < TPAD)
    float* Mp = Mpart + (size_t)(jc * BEH + be) * DE * MPSTRIDE;
    const int s = s0 + wave * 16 + l16;
    #pragma unroll
    for (int i = 0; i < 4; ++i) {
        #pragma unroll
        for (int r = 0; r < 4; ++r) {
            const int d = i * 16 + quad * 4 + r;
            Mp[(size_t)d * MPSTRIDE + s] = acc[i][r];
        }
    }
}

// ---------------------------------------------------------------------------
// Kernel 2b: reduce the 4 j-chunk partials -> bf16 Mt[be][d][TPAD].
// ---------------------------------------------------------------------------
__global__ __launch_bounds__(256) void mreduce_kernel(
    const float* __restrict__ Mpart, short* __restrict__ Mt)
{
    const int g = blockIdx.x * 256 + threadIdx.x;
    const int NG = TPAD / 4;                        // 416
    if (g >= BEH * DE * NG) return;
    const int bd = g / NG;
    const int s4 = (g - bd * NG) * 4;

    const size_t jstride = (size_t)BEH * DE * MPSTRIDE;
    const float* p = Mpart + (size_t)bd * MPSTRIDE + s4;
    float4 a0 = *(const float4*)(p);
    float4 a1 = *(const float4*)(p + jstride);
    float4 a2 = *(const float4*)(p + 2 * jstride);
    float4 a3 = *(const float4*)(p + 3 * jstride);
    float s0 = a0.x + a1.x + a2.x + a3.x;
    float s1 = a0.y + a1.y + a2.y + a3.y;
    float s2 = a0.z + a1.z + a2.z + a3.z;
    float s3 = a0.w + a1.w + a2.w + a3.w;

    uint2 o;
    o.x = pack2(s0, s1);
    o.y = pack2(s2, s3);
    *(uint2*)(Mt + (size_t)bd * TPAD + s4) = o;
}

// ---------------------------------------------------------------------------
// Kernel 3 (MFMA): fused attention. v3:
//   - Wl folded into Ps buffer (each element read-then-overwritten by its
//     owning lane; wave-private rows) -> LDS 46 -> 36.9 KB -> 4 blocks/CU.
//   - 2-deep register prefetch of K/M/P staging (was fully exposed per tile).
// ---------------------------------------------------------------------------
struct AStage {
    uint4 k0, k1, m0, m1, p0, p1;
};

__global__ __launch_bounds__(256, 4) void attn3_kernel(
    const short* __restrict__ Qb, const short* __restrict__ Kb,
    const short* __restrict__ Mt, const short* __restrict__ Pbf,
    float* __restrict__ Hbuf)
{
    __shared__ __align__(16) short Qs[64][72];  // [i][d]
    __shared__ __align__(16) short Ks[64][72];  // [s][d]
    __shared__ __align__(16) short Ms[64][72];  // [d][s]
    __shared__ __align__(16) short Ps[64][72];  // [i][s]: punish tile, then Wl

    const int it = blockIdx.x, be = blockIdx.y;
    const int b = be >> 3, e = be & 7;
    const int i0 = it * 64;
    const short* Qh = Qb + (size_t)be * DE * TT;
    const short* Kh = Kb + (size_t)be * DE * TT;
    const short* Mh = Mt + (size_t)be * DE * TPAD;

    const int tid  = threadIdx.x;
    const int wave = tid >> 6, lane = tid & 63;
    const int quad = lane >> 4, l16 = lane & 15;

    const float invs = 0.024598297f;  // 1/sqrt(1653)

    const int srow = tid >> 2, scg = (tid & 3) * 16;
    const int gi = i0 + srow;
    const bool giv = (gi < TT);

    {   // Q: staged once, never overwritten
        uint4 z = make_uint4(0u, 0u, 0u, 0u);
        uint4 v0 = z, v1 = z;
        if (giv) {
            v0 = *(const uint4*)(Qh + (size_t)gi * DE + scg);
            v1 = *(const uint4*)(Qh + (size_t)gi * DE + scg + 8);
        }
        *(uint4*)&Qs[srow][scg]     = v0;
        *(uint4*)&Qs[srow][scg + 8] = v1;
    }

    f32x4 out[4];
    #pragma unroll
    for (int i = 0; i < 4; ++i) out[i] = (f32x4){0.f, 0.f, 0.f, 0.f};

    auto stage_regs = [&](AStage& S, int s0) {
        const uint4 z = make_uint4(0u, 0u, 0u, 0u);
        const int gs = s0 + srow;
        S.k0 = z; S.k1 = z;
        if (gs < TT) {
            S.k0 = *(const uint4*)(Kh + (size_t)gs * DE + scg);
            S.k1 = *(const uint4*)(Kh + (size_t)gs * DE + scg + 8);
        }
        S.m0 = *(const uint4*)(Mh + (size_t)srow * TPAD + s0 + scg);
        S.m1 = *(const uint4*)(Mh + (size_t)srow * TPAD + s0 + scg + 8);
        S.p0 = z; S.p1 = z;
        if (giv) {
            S.p0 = *(const uint4*)(Pbf + (size_t)gi * TPAD + s0 + scg);
            S.p1 = *(const uint4*)(Pbf + (size_t)gi * TPAD + s0 + scg + 8);
        }
    };

    auto lds_write = [&](const AStage& S) {
        *(uint4*)&Ks[srow][scg]     = S.k0;
        *(uint4*)&Ks[srow][scg + 8] = S.k1;
        *(uint4*)&Ms[srow][scg]     = S.m0;
        *(uint4*)&Ms[srow][scg + 8] = S.m1;
        *(uint4*)&Ps[srow][scg]     = S.p0;
        *(uint4*)&Ps[srow][scg + 8] = S.p1;
    };

    auto compute = [&]() {
        f32x4 w[4];
        #pragma unroll
        for (int i = 0; i < 4; ++i) w[i] = (f32x4){0.f, 0.f, 0.f, 0.f};
        #pragma unroll
        for (int ks = 0; ks < 2; ++ks) {
            bf16x8 a = *(const bf16x8*)&Qs[wave * 16 + l16][ks * 32 + quad * 8];
            #pragma unroll
            for (int stile = 0; stile < 4; ++stile) {
                bf16x8 bb = *(const bf16x8*)&Ks[stile * 16 + l16][ks * 32 + quad * 8];
                w[stile] = __builtin_amdgcn_mfma_f32_16x16x32_bf16(a, bb, w[stile], 0, 0, 0);
            }
        }

        // scale by punish, write Wl back into the Ps buffer (read-then-write
        // by the same lane per element; rows are wave-private)
        #pragma unroll
        for (int stile = 0; stile < 4; ++stile) {
            const int sl = stile * 16 + l16;
            #pragma unroll
            for (int r = 0; r < 4; ++r) {
                const int il = wave * 16 + quad * 4 + r;
                float v = w[stile][r] * invs * bf2f(Ps[il][sl]);
                Ps[il][sl] = f2bf(v);
            }
        }

        #pragma unroll
        for (int ks = 0; ks < 2; ++ks) {
            bf16x8 a = *(const bf16x8*)&Ps[wave * 16 + l16][ks * 32 + quad * 8];
            #pragma unroll
            for (int dt = 0; dt < 4; ++dt) {
                bf16x8 bb = *(const bf16x8*)&Ms[dt * 16 + l16][ks * 32 + quad * 8];
                out[dt] = __builtin_amdgcn_mfma_f32_16x16x32_bf16(a, bb, out[dt], 0, 0, 0);
            }
        }
    };

    AStage sA, sB;
    stage_regs(sA, 0);
    stage_regs(sB, 64);

    for (int tt = 0; tt < TTILES; tt += 2) {
        if (tt) __syncthreads();
        lds_write(sA);
        if (tt + 2 < TTILES) stage_regs(sA, (tt + 2) * 64);
        __syncthreads();
        compute();
        __syncthreads();
        lds_write(sB);
        if (tt + 3 < TTILES) stage_regs(sB, (tt + 3) * 64);
        __syncthreads();
        compute();
    }

    #pragma unroll
    for (int dt = 0; dt < 4; ++dt) {
        const int d = dt * 16 + l16;
        #pragma unroll
        for (int r = 0; r < 4; ++r) {
            const int go = i0 + wave * 16 + quad * 4 + r;
            if (go < TT)
                Hbuf[((size_t)b * TT + go) * DD + e * 64 + d] = out[dt][r];
        }
    }
}

// ---------------------------------------------------------------------------
// Kernel 4: final projection (fp32 SGEMM, precision anchor for the output).
// ---------------------------------------------------------------------------
__global__ __launch_bounds__(256) void oproj_kernel(
    const float* __restrict__ H, const float* __restrict__ Wo,
    const float* __restrict__ bo, float* __restrict__ out)
{
    __shared__ float Hs[16][68];
    __shared__ float Ns[16][68];

    const int tt = blockIdx.x, nt = blockIdx.y, b = blockIdx.z;
    const int t0 = tt * 64, n0 = nt * 64;
    const float* Hb = H + (size_t)b * TT * DD;

    const int tid = threadIdx.x;
    const int tx = tid & 15, ty = tid >> 4;
    const int lrow = tid >> 2, lq = tid & 3;
    const int trow = t0 + lrow;

    float acc[4][4] = {};

    for (int k0 = 0; k0 < DD; k0 += 16) {
        float4 hv = make_float4(0.f, 0.f, 0.f, 0.f);
        if (trow < TT)
            hv = *(const float4*)(Hb + (size_t)trow * DD + k0 + lq*4);
        float4 wv = *(const float4*)(Wo + (size_t)(n0 + lrow) * DD + k0 + lq*4);
        __syncthreads();
        Hs[lq*4+0][lrow] = hv.x; Hs[lq*4+1][lrow] = hv.y;
        Hs[lq*4+2][lrow] = hv.z; Hs[lq*4+3][lrow] = hv.w;
        Ns[lq*4+0][lrow] = wv.x; Ns[lq*4+1][lrow] = wv.y;
        Ns[lq*4+2][lrow] = wv.z; Ns[lq*4+3][lrow] = wv.w;
        __syncthreads();
        #pragma unroll
        for (int k = 0; k < 16; ++k) {
            float4 a4 = *(const float4*)(&Hs[k][ty*4]);
            float4 c4 = *(const float4*)(&Ns[k][tx*4]);
            float a[4] = {a4.x, a4.y, a4.z, a4.w};
            float c[4] = {c4.x, c4.y, c4.z, c4.w};
            #pragma unroll
            for (int i = 0; i < 4; ++i)
                #pragma unroll
                for (int j = 0; j < 4; ++j)
                    acc[i][j] = fmaf(a[i], c[j], acc[i][j]);
        }
        __syncthreads();
    }

    #pragma unroll
    for (int i = 0; i < 4; ++i) {
        const int t = t0 + ty*4 + i;
        if (t < TT) {
            float4 v;
            v.x = acc[i][0] + bo[n0 + tx*4 + 0];
            v.y = acc[i][1] + bo[n0 + tx*4 + 1];
            v.z = acc[i][2] + bo[n0 + tx*4 + 2];
            v.w = acc[i][3] + bo[n0 + tx*4 + 3];
            *(float4*)(out + ((size_t)b * TT + t) * DD + n0 + tx*4) = v;
        }
    }
}

// ---------------------------------------------------------------------------
extern "C" void kernel_launch(void* const* d_in, const int* in_sizes, int n_in,
                              void* d_out, int out_size, void* d_ws, size_t ws_size,
                              hipStream_t stream)
{
    (void)in_sizes; (void)n_in; (void)out_size; (void)ws_size;

    const float* X    = (const float*)d_in[0];
    const float* Wq   = (const float*)d_in[1];
    const float* bq   = (const float*)d_in[2];
    const float* Wk   = (const float*)d_in[3];
    const float* bk   = (const float*)d_in[4];
    const float* Wv   = (const float*)d_in[5];
    const float* bv   = (const float*)d_in[6];
    const float* Wo   = (const float*)d_in[7];
    const float* bo   = (const float*)d_in[8];
    const float* P    = (const float*)d_in[9];
    const float* orth = (const float*)d_in[10];
    float* out = (float*)d_out;

    // Workspace layout (~46.3 MB):
    //   Qb/Kb/Vb bf16 [B*D*T]        3 x 3,385,344 B
    //   Mtb      bf16 [BE*64*TPAD]       3,407,872 B
    //   Pbf      bf16 [T*TPAD]           5,501,184 B
    //   Mpart    fp32 [4][BE*64][TPAD]  27,262,976 B  (dead after mreduce)
    //   Hbuf     fp32 [B*T*D] -- ALIASES Mpart (written by attn after mreduce)
    char* ws = (char*)d_ws;
    const size_t SZH = (size_t)BB * DD * TT * sizeof(short);
    short* Qb  = (short*)(ws);
    short* Kb  = (short*)(ws + SZH);
    short* Vb  = (short*)(ws + 2 * SZH);
    short* Mtb = (short*)(ws + 3 * SZH);
    short* Pbf = (short*)(ws + 3 * SZH + (size_t)BEH * DE * TPAD * sizeof(short));
    char*  after_p = ws + 3 * SZH + (size_t)BEH * DE * TPAD * sizeof(short)
                        + (size_t)TT * TPAD * sizeof(short);
    float* Mpart = (float*)after_p;
    float* Hbuf  = (float*)after_p;   // alias: Mpart dead before attn runs

    dim3 blk(256);

    convp2_kernel<<<dim3((TT * (TPAD / 4) + 255) / 256), blk, 0, stream>>>(P, Pbf);

    dim3 g1(TTILES, DD / 64, BB * 3);
    proj3_kernel<<<g1, blk, 0, stream>>>(X, Wq, bq, Wk, bk, Wv, bv, Qb, Kb, Vb);

    dim3 g2(SQN, BEH, NJC);
    ovt5_kernel<<<g2, blk, 0, stream>>>(orth, Vb, Mpart);

    dim3 gr((BEH * DE * (TPAD / 4) + 255) / 256);
    mreduce_kernel<<<gr, blk, 0, stream>>>(Mpart, Mtb);

    dim3 g3(TTILES, BEH);
    attn3_kernel<<<g3, blk, 0, stream>>>(Qb, Kb, Mtb, Pbf, Hbuf);

    dim3 g4(TTILES, DD / 64, BB);
    oproj_kernel<<<g4, blk, 0, stream>>>(Hbuf, Wo, bo, out);
}

// Round 3
// 406.529 us; speedup vs baseline: 1.0469x; 1.0036x over previous
//
#include <hip/hip_runtime.h>

// Sizes fixed by the problem.
#define TT 1653          // T
#define DD 512           // D
#define BB 2             // B
#define DE 64            // D/E
#define BEH 16           // B*E
#define TTILES 26        // ceil(T/64)
#define TPAD 1664        // T padded to multiple of 64
#define SQN 26           // ovt s-tiles (TPAD/64)
#define NJC 4            // ovt j-split
#define MPSTRIDE TPAD    // Mpart row stride (floats)

typedef __attribute__((ext_vector_type(8))) short bf16x8;   // 8 bf16 (4 VGPRs)
typedef __attribute__((ext_vector_type(4))) float f32x4;
typedef float f32x4u  __attribute__((ext_vector_type(4), aligned(4)));  // O rows only 4B-aligned (TT odd)

__device__ __forceinline__ short f2bf(float f) {
    union { float f; unsigned u; } v; v.f = f;
    unsigned r = v.u + 0x7fffu + ((v.u >> 16) & 1u);   // RNE
    return (short)(r >> 16);
}
__device__ __forceinline__ unsigned pack2(float a, float b) {
    return (unsigned)(unsigned short)f2bf(a) | ((unsigned)(unsigned short)f2bf(b) << 16);
}
__device__ __forceinline__ float bf2f(short s) {
    union { unsigned u; float f; } v; v.u = ((unsigned)(unsigned short)s) << 16;
    return v.f;
}

// Raw barriers: NO implicit vmcnt(0) drain (that's __syncthreads' semantics).
// Compiler still emits exact counted vmcnt waits at each staged-register use,
// so prefetched global loads stay in flight ACROSS barriers (T3/T4).
// sched_barrier(0) fences per rule #18 (keep codegen from crossing).
__device__ __forceinline__ void bar_fenced() {
    __builtin_amdgcn_sched_barrier(0);
    __builtin_amdgcn_s_barrier();
    __builtin_amdgcn_sched_barrier(0);
}
__device__ __forceinline__ void lgkm0_bar() {
    asm volatile("s_waitcnt lgkmcnt(0)" ::: "memory");   // our ds_writes visible
    __builtin_amdgcn_sched_barrier(0);
    __builtin_amdgcn_s_barrier();
    __builtin_amdgcn_sched_barrier(0);
}

// ---------------------------------------------------------------------------
// Kernel 0: punish matrix -> bf16 [T][TPAD], zero pad cols.
// ---------------------------------------------------------------------------
__global__ __launch_bounds__(256) void convp2_kernel(
    const float* __restrict__ P, short* __restrict__ Pbf)
{
    const int g = blockIdx.x * 256 + threadIdx.x;
    const int NG4 = TPAD / 4;                       // 416
    if (g >= TT * NG4) return;
    const int r = g / NG4, c4 = (g - r * NG4) * 4;
    float p0 = 0.f, p1 = 0.f, p2 = 0.f, p3 = 0.f;
    const float* prow = P + (size_t)r * TT;
    if (c4 + 0 < TT) p0 = prow[c4 + 0];
    if (c4 + 1 < TT) p1 = prow[c4 + 1];
    if (c4 + 2 < TT) p2 = prow[c4 + 2];
    if (c4 + 3 < TT) p3 = prow[c4 + 3];
    uint2 o; o.x = pack2(p0, p1); o.y = pack2(p2, p3);
    *(uint2*)(Pbf + (size_t)r * TPAD + c4) = o;
}

// ---------------------------------------------------------------------------
// Kernel 1 (MFMA): projections Q/K/V in [B, D, T] scramble layout, bf16 out.
// v4: raw counted barriers (loads span barriers).
// ---------------------------------------------------------------------------
__global__ __launch_bounds__(256) void proj4_kernel(
    const float* __restrict__ X,
    const float* __restrict__ W0, const float* __restrict__ b0,
    const float* __restrict__ W1, const float* __restrict__ b1,
    const float* __restrict__ W2, const float* __restrict__ b2,
    short* __restrict__ Y0, short* __restrict__ Y1, short* __restrict__ Y2)
{
    __shared__ __align__(16) short Wsh[64][72];  // [d][k] bf16
    __shared__ __align__(16) short Xs[64][72];   // [t][k] bf16

    const int tt = blockIdx.x, dt = blockIdx.y, z = blockIdx.z;
    const int b = z / 3, which = z % 3;
    const float* W    = (which == 0) ? W0 : (which == 1) ? W1 : W2;
    const float* bias = (which == 0) ? b0 : (which == 1) ? b1 : b2;
    short* Y          = (which == 0) ? Y0 : (which == 1) ? Y1 : Y2;

    const int t0 = tt * 64, d0 = dt * 64;
    const float* Xb = X + (size_t)b * TT * DD;

    const int tid  = threadIdx.x;
    const int wave = tid >> 6, lane = tid & 63;
    const int quad = lane >> 4, l16 = lane & 15;
    const int srow = tid >> 2, scg = (tid & 3) * 16;
    const int trow = t0 + srow;
    const int rx = min(trow, TT - 1);   // clamped row (select at write time)

    f32x4 acc[4];
    #pragma unroll
    for (int i = 0; i < 4; ++i) acc[i] = (f32x4){0.f, 0.f, 0.f, 0.f};

    float4 w0, w1, w2, w3, x0, x1, x2, x3;

    auto stage = [&](int k0) {   // raw loads only; no value use here
        const float* wrow = W + (size_t)(d0 + srow) * DD + k0 + scg;
        w0 = *(const float4*)(wrow);
        w1 = *(const float4*)(wrow + 4);
        w2 = *(const float4*)(wrow + 8);
        w3 = *(const float4*)(wrow + 12);
        const float* xrow = Xb + (size_t)rx * DD + k0 + scg;
        x0 = *(const float4*)(xrow);
        x1 = *(const float4*)(xrow + 4);
        x2 = *(const float4*)(xrow + 8);
        x3 = *(const float4*)(xrow + 12);
    };
    auto lds_write = [&]() {
        const bool tv = (trow < TT);
        float4 zz = make_float4(0.f, 0.f, 0.f, 0.f);
        float4 y0 = tv ? x0 : zz, y1 = tv ? x1 : zz;
        float4 y2 = tv ? x2 : zz, y3 = tv ? x3 : zz;
        uint4 pw0, pw1, px0, px1;
        pw0.x = pack2(w0.x, w0.y); pw0.y = pack2(w0.z, w0.w);
        pw0.z = pack2(w1.x, w1.y); pw0.w = pack2(w1.z, w1.w);
        pw1.x = pack2(w2.x, w2.y); pw1.y = pack2(w2.z, w2.w);
        pw1.z = pack2(w3.x, w3.y); pw1.w = pack2(w3.z, w3.w);
        px0.x = pack2(y0.x, y0.y); px0.y = pack2(y0.z, y0.w);
        px0.z = pack2(y1.x, y1.y); px0.w = pack2(y1.z, y1.w);
        px1.x = pack2(y2.x, y2.y); px1.y = pack2(y2.z, y2.w);
        px1.z = pack2(y3.x, y3.y); px1.w = pack2(y3.z, y3.w);
        *(uint4*)&Wsh[srow][scg]     = pw0;
        *(uint4*)&Wsh[srow][scg + 8] = pw1;
        *(uint4*)&Xs[srow][scg]      = px0;
        *(uint4*)&Xs[srow][scg + 8]  = px1;
    };

    stage(0);
    for (int k0 = 0; k0 < DD; k0 += 64) {
        lds_write();
        if (k0 + 64 < DD) stage(k0 + 64);   // stays in flight across barriers
        lgkm0_bar();

        #pragma unroll
        for (int ks = 0; ks < 2; ++ks) {
            bf16x8 a = *(const bf16x8*)&Wsh[wave * 16 + l16][ks * 32 + quad * 8];
            #pragma unroll
            for (int nt = 0; nt < 4; ++nt) {
                bf16x8 bb = *(const bf16x8*)&Xs[nt * 16 + l16][ks * 32 + quad * 8];
                acc[nt] = __builtin_amdgcn_mfma_f32_16x16x32_bf16(a, bb, acc[nt], 0, 0, 0);
            }
        }
        bar_fenced();
    }

    #pragma unroll
    for (int nt = 0; nt < 4; ++nt) {
        const int t = t0 + nt * 16 + l16;
        if (t < TT) {
            #pragma unroll
            for (int r = 0; r < 4; ++r) {
                const int d = d0 + wave * 16 + quad * 4 + r;
                float v = acc[nt][r] + bias[d];
                if (which < 2) v = 1.2f / (1.0f + __expf(-1.6f * v));
                Y[((size_t)b * DD + d) * TT + t] = f2bf(v);
            }
        }
    }
}

// ---------------------------------------------------------------------------
// Kernel 2 (MFMA): partial Mt.  v6 — ovt5 + raw counted barriers.
//   Mpart[jc][be][d][s] = sum_{j in chunk jc} V[j][d] * O[j][s]
// Theory: __syncthreads drained vmcnt(0) every barrier -> the 2-deep register
// prefetch never had loads in flight across a barrier -> every tile paid full
// HBM latency (ovt3/4/5 all ~1.4 TB/s regardless of access pattern). Raw
// s_barrier + compiler-counted vmcnt keeps the other stage-set's 8 loads in
// flight at all times.
// ---------------------------------------------------------------------------
struct OVStage {
    f32x4u o0a, o0b, o1a, o1b;    // O rows j0+2p, +1, +32, +33 ; cols 4sc..+3
    uint2  v0a, v0b, v1a, v1b;    // V same rows ; d cols 4sc..+3 (raw, clamped rows)
};

__global__ __launch_bounds__(256) void ovt6_kernel(
    const float* __restrict__ orth, const short* __restrict__ Vb,
    float* __restrict__ Mpart)
{
    __shared__ __align__(16) short Os[64][72];  // [s_local][j_local] bf16
    __shared__ __align__(16) short Vs[64][72];  // [d][j_local] bf16

    const int sq = blockIdx.x, be = blockIdx.y, jc = blockIdx.z;
    const int s0 = sq * 64;
    const int jt0 = (jc < 2) ? jc * 7 : 14 + (jc - 2) * 6;   // tiles {7,7,6,6}
    const int jtn = (jc < 2) ? 7 : 6;

    const float* O  = orth + (size_t)be * TT * TT;
    const short* Vh = Vb + (size_t)be * DE * TT;   // head block, scramble [j][64]

    const int tid  = threadIdx.x;
    const int wave = tid >> 6, lane = tid & 63;
    const int quad = lane >> 4, l16 = lane & 15;

    const int p  = tid & 15;          // j-pair index (pairs p and p+16)
    const int sc = tid >> 4;          // col group 0..15: local cols 4sc..4sc+3
    const int ca = s0 + 4 * sc;       // global col base
    const bool fastS = (s0 + 64 <= TT);   // all 64 cols in range (sq <= 24)

    f32x4 acc[4];
    #pragma unroll
    for (int i = 0; i < 4; ++i) acc[i] = (f32x4){0.f, 0.f, 0.f, 0.f};

    auto stage_load = [&](OVStage& S, int j0) {   // raw loads only
        const int jA = j0 + 2 * p;
        const int r0  = min(jA,      TT - 1);
        const int r0b = min(jA + 1,  TT - 1);
        const int r1  = min(jA + 32, TT - 1);
        const int r1b = min(jA + 33, TT - 1);
        if (fastS) {
            S.o0a = *(const f32x4u*)(O + (size_t)r0  * TT + ca);
            S.o0b = *(const f32x4u*)(O + (size_t)r0b * TT + ca);
            S.o1a = *(const f32x4u*)(O + (size_t)r1  * TT + ca);
            S.o1b = *(const f32x4u*)(O + (size_t)r1b * TT + ca);
        } else {
            #pragma unroll
            for (int i = 0; i < 4; ++i) {
                const int col = ca + i;
                const bool cv = (col < TT);
                S.o0a[i] = cv ? O[(size_t)r0  * TT + col] : 0.f;
                S.o0b[i] = cv ? O[(size_t)r0b * TT + col] : 0.f;
                S.o1a[i] = cv ? O[(size_t)r1  * TT + col] : 0.f;
                S.o1b[i] = cv ? O[(size_t)r1b * TT + col] : 0.f;
            }
        }
        S.v0a = *(const uint2*)(Vh + (size_t)r0  * DE + 4 * sc);
        S.v0b = *(const uint2*)(Vh + (size_t)r0b * DE + 4 * sc);
        S.v1a = *(const uint2*)(Vh + (size_t)r1  * DE + 4 * sc);
        S.v1b = *(const uint2*)(Vh + (size_t)r1b * DE + 4 * sc);
    };

    auto lds_write = [&](const OVStage& S, int j0) {
        const int jA = j0 + 2 * p;
        // O transpose-pack: 2-way bank aliasing (free).
        #pragma unroll
        for (int i = 0; i < 4; ++i) {
            *(unsigned*)&Os[4 * sc + i][2 * p]      = pack2(S.o0a[i], S.o0b[i]);
            *(unsigned*)&Os[4 * sc + i][2 * p + 32] = pack2(S.o1a[i], S.o1b[i]);
        }
        // V transpose: zero pad-j rows here (kills pad-j MFMA contributions)
        const uint2 z = make_uint2(0u, 0u);
        uint2 v0a = (jA      < TT) ? S.v0a : z;
        uint2 v0b = (jA + 1  < TT) ? S.v0b : z;
        uint2 v1a = (jA + 32 < TT) ? S.v1a : z;
        uint2 v1b = (jA + 33 < TT) ? S.v1b : z;
        *(unsigned*)&Vs[4 * sc + 0][2 * p]      = (v0a.x & 0xffffu) | (v0b.x << 16);
        *(unsigned*)&Vs[4 * sc + 1][2 * p]      = (v0a.x >> 16)     | (v0b.x & 0xffff0000u);
        *(unsigned*)&Vs[4 * sc + 2][2 * p]      = (v0a.y & 0xffffu) | (v0b.y << 16);
        *(unsigned*)&Vs[4 * sc + 3][2 * p]      = (v0a.y >> 16)     | (v0b.y & 0xffff0000u);
        *(unsigned*)&Vs[4 * sc + 0][2 * p + 32] = (v1a.x & 0xffffu) | (v1b.x << 16);
        *(unsigned*)&Vs[4 * sc + 1][2 * p + 32] = (v1a.x >> 16)     | (v1b.x & 0xffff0000u);
        *(unsigned*)&Vs[4 * sc + 2][2 * p + 32] = (v1a.y & 0xffffu) | (v1b.y << 16);
        *(unsigned*)&Vs[4 * sc + 3][2 * p + 32] = (v1a.y >> 16)     | (v1b.y & 0xffff0000u);
    };

    auto mfma_tile = [&]() {
        #pragma unroll
        for (int ks = 0; ks < 2; ++ks) {
            bf16x8 bb = *(const bf16x8*)&Os[wave * 16 + l16][ks * 32 + quad * 8];
            #pragma unroll
            for (int i = 0; i < 4; ++i) {
                bf16x8 a = *(const bf16x8*)&Vs[i * 16 + l16][ks * 32 + quad * 8];
                acc[i] = __builtin_amdgcn_mfma_f32_16x16x32_bf16(a, bb, acc[i], 0, 0, 0);
            }
        }
    };

    OVStage sA, sB;
    stage_load(sA, (jt0 + 0) * 64);
    stage_load(sB, (jt0 + 1) * 64);

    for (int t = 0; t < jtn; t += 2) {
        lds_write(sA, (jt0 + t) * 64);            // compiler waits sA only
        if (t + 2 < jtn) stage_load(sA, (jt0 + t + 2) * 64);
        lgkm0_bar();
        mfma_tile();
        bar_fenced();
        if (t + 1 < jtn) {
            lds_write(sB, (jt0 + t + 1) * 64);
            if (t + 3 < jtn) stage_load(sB, (jt0 + t + 3) * 64);
            lgkm0_bar();
            mfma_tile();
            bar_fenced();
        }
    }

    // epilogue: d = i*16+quad*4+r, s = s0 + wave*16 + l16 (always < TPAD)
    float* Mp = Mpart + (size_t)(jc * BEH + be) * DE * MPSTRIDE;
    const int s = s0 + wave * 16 + l16;
    #pragma unroll
    for (int i = 0; i < 4; ++i) {
        #pragma unroll
        for (int r = 0; r < 4; ++r) {
            const int d = i * 16 + quad * 4 + r;
            Mp[(size_t)d * MPSTRIDE + s] = acc[i][r];
        }
    }
}

// ---------------------------------------------------------------------------
// Kernel 2b: reduce the 4 j-chunk partials -> bf16 Mt[be][d][TPAD].
// ---------------------------------------------------------------------------
__global__ __launch_bounds__(256) void mreduce_kernel(
    const float* __restrict__ Mpart, short* __restrict__ Mt)
{
    const int g = blockIdx.x * 256 + threadIdx.x;
    const int NG = TPAD / 4;                        // 416
    if (g >= BEH * DE * NG) return;
    const int bd = g / NG;
    const int s4 = (g - bd * NG) * 4;

    const size_t jstride = (size_t)BEH * DE * MPSTRIDE;
    const float* p = Mpart + (size_t)bd * MPSTRIDE + s4;
    float4 a0 = *(const float4*)(p);
    float4 a1 = *(const float4*)(p + jstride);
    float4 a2 = *(const float4*)(p + 2 * jstride);
    float4 a3 = *(const float4*)(p + 3 * jstride);
    float s0 = a0.x + a1.x + a2.x + a3.x;
    float s1 = a0.y + a1.y + a2.y + a3.y;
    float s2 = a0.z + a1.z + a2.z + a3.z;
    float s3 = a0.w + a1.w + a2.w + a3.w;

    uint2 o;
    o.x = pack2(s0, s1);
    o.y = pack2(s2, s3);
    *(uint2*)(Mt + (size_t)bd * TPAD + s4) = o;
}

// ---------------------------------------------------------------------------
// Kernel 3 (MFMA): fused attention. v4 — raw counted barriers, deferred
// validity selects (raw clamped loads at stage time).
// ---------------------------------------------------------------------------
struct AStage {
    uint4 k0, k1, m0, m1, p0, p1;
};

__global__ __launch_bounds__(256) void attn4_kernel(
    const short* __restrict__ Qb, const short* __restrict__ Kb,
    const short* __restrict__ Mt, const short* __restrict__ Pbf,
    float* __restrict__ Hbuf)
{
    __shared__ __align__(16) short Qs[64][72];  // [i][d]
    __shared__ __align__(16) short Ks[64][72];  // [s][d]
    __shared__ __align__(16) short Ms[64][72];  // [d][s]
    __shared__ __align__(16) short Ps[64][72];  // [i][s]: punish tile, then Wl

    const int it = blockIdx.x, be = blockIdx.y;
    const int b = be >> 3, e = be & 7;
    const int i0 = it * 64;
    const short* Qh = Qb + (size_t)be * DE * TT;
    const short* Kh = Kb + (size_t)be * DE * TT;
    const short* Mh = Mt + (size_t)be * DE * TPAD;

    const int tid  = threadIdx.x;
    const int wave = tid >> 6, lane = tid & 63;
    const int quad = lane >> 4, l16 = lane & 15;

    const float invs = 0.024598297f;  // 1/sqrt(1653)

    const int srow = tid >> 2, scg = (tid & 3) * 16;
    const int gi = i0 + srow;
    const bool giv = (gi < TT);
    const int ri = min(gi, TT - 1);

    {   // Q: staged once, never overwritten (drains only its own 2 loads)
        uint4 z = make_uint4(0u, 0u, 0u, 0u);
        uint4 v0 = *(const uint4*)(Qh + (size_t)ri * DE + scg);
        uint4 v1 = *(const uint4*)(Qh + (size_t)ri * DE + scg + 8);
        if (!giv) { v0 = z; v1 = z; }
        *(uint4*)&Qs[srow][scg]     = v0;
        *(uint4*)&Qs[srow][scg + 8] = v1;
    }

    f32x4 out[4];
    #pragma unroll
    for (int i = 0; i < 4; ++i) out[i] = (f32x4){0.f, 0.f, 0.f, 0.f};

    auto stage_regs = [&](AStage& S, int s0) {   // raw clamped loads only
        const int gs = s0 + srow;
        const int rs = min(gs, TT - 1);
        S.k0 = *(const uint4*)(Kh + (size_t)rs * DE + scg);
        S.k1 = *(const uint4*)(Kh + (size_t)rs * DE + scg + 8);
        S.m0 = *(const uint4*)(Mh + (size_t)srow * TPAD + s0 + scg);
        S.m1 = *(const uint4*)(Mh + (size_t)srow * TPAD + s0 + scg + 8);
        S.p0 = *(const uint4*)(Pbf + (size_t)ri * TPAD + s0 + scg);
        S.p1 = *(const uint4*)(Pbf + (size_t)ri * TPAD + s0 + scg + 8);
    };

    auto lds_write = [&](const AStage& S, int s0) {
        const int gs = s0 + srow;
        const uint4 z = make_uint4(0u, 0u, 0u, 0u);
        const bool kv = (gs < TT);
        uint4 k0 = kv ? S.k0 : z, k1 = kv ? S.k1 : z;
        uint4 p0 = giv ? S.p0 : z, p1 = giv ? S.p1 : z;
        *(uint4*)&Ks[srow][scg]     = k0;
        *(uint4*)&Ks[srow][scg + 8] = k1;
        *(uint4*)&Ms[srow][scg]     = S.m0;
        *(uint4*)&Ms[srow][scg + 8] = S.m1;
        *(uint4*)&Ps[srow][scg]     = p0;
        *(uint4*)&Ps[srow][scg + 8] = p1;
    };

    auto compute = [&]() {
        f32x4 w[4];
        #pragma unroll
        for (int i = 0; i < 4; ++i) w[i] = (f32x4){0.f, 0.f, 0.f, 0.f};
        #pragma unroll
        for (int ks = 0; ks < 2; ++ks) {
            bf16x8 a = *(const bf16x8*)&Qs[wave * 16 + l16][ks * 32 + quad * 8];
            #pragma unroll
            for (int stile = 0; stile < 4; ++stile) {
                bf16x8 bb = *(const bf16x8*)&Ks[stile * 16 + l16][ks * 32 + quad * 8];
                w[stile] = __builtin_amdgcn_mfma_f32_16x16x32_bf16(a, bb, w[stile], 0, 0, 0);
            }
        }

        // scale by punish, write Wl back into the Ps buffer (wave-private rows)
        #pragma unroll
        for (int stile = 0; stile < 4; ++stile) {
            const int sl = stile * 16 + l16;
            #pragma unroll
            for (int r = 0; r < 4; ++r) {
                const int il = wave * 16 + quad * 4 + r;
                float v = w[stile][r] * invs * bf2f(Ps[il][sl]);
                Ps[il][sl] = f2bf(v);
            }
        }

        #pragma unroll
        for (int ks = 0; ks < 2; ++ks) {
            bf16x8 a = *(const bf16x8*)&Ps[wave * 16 + l16][ks * 32 + quad * 8];
            #pragma unroll
            for (int dt = 0; dt < 4; ++dt) {
                bf16x8 bb = *(const bf16x8*)&Ms[dt * 16 + l16][ks * 32 + quad * 8];
                out[dt] = __builtin_amdgcn_mfma_f32_16x16x32_bf16(a, bb, out[dt], 0, 0, 0);
            }
        }
    };

    AStage sA, sB;
    stage_regs(sA, 0);
    stage_regs(sB, 64);
    lgkm0_bar();   // Qs visible; sA/sB loads remain in flight (no vmcnt drain)

    for (int tt = 0; tt < TTILES; tt += 2) {
        lds_write(sA, tt * 64);                       // waits sA only
        if (tt + 2 < TTILES) stage_regs(sA, (tt + 2) * 64);
        lgkm0_bar();
        compute();
        bar_fenced();
        lds_write(sB, (tt + 1) * 64);
        if (tt + 3 < TTILES) stage_regs(sB, (tt + 3) * 64);
        lgkm0_bar();
        compute();
        bar_fenced();
    }

    #pragma unroll
    for (int dt = 0; dt < 4; ++dt) {
        const int d = dt * 16 + l16;
        #pragma unroll
        for (int r = 0; r < 4; ++r) {
            const int go = i0 + wave * 16 + quad * 4 + r;
            if (go < TT)
                Hbuf[((size_t)b * TT + go) * DD + e * 64 + d] = out[dt][r];
        }
    }
}

// ---------------------------------------------------------------------------
// Kernel 4: final projection (fp32 SGEMM, precision anchor for the output).
// ---------------------------------------------------------------------------
__global__ __launch_bounds__(256) void oproj_kernel(
    const float* __restrict__ H, const float* __restrict__ Wo,
    const float* __restrict__ bo, float* __restrict__ out)
{
    __shared__ float Hs[16][68];
    __shared__ float Ns[16][68];

    const int tt = blockIdx.x, nt = blockIdx.y, b = blockIdx.z;
    const int t0 = tt * 64, n0 = nt * 64;
    const float* Hb = H + (size_t)b * TT * DD;

    const int tid = threadIdx.x;
    const int tx = tid & 15, ty = tid >> 4;
    const int lrow = tid >> 2, lq = tid & 3;
    const int trow = t0 + lrow;

    float acc[4][4] = {};

    for (int k0 = 0; k0 < DD; k0 += 16) {
        float4 hv = make_float4(0.f, 0.f, 0.f, 0.f);
        if (trow < TT)
            hv = *(const float4*)(Hb + (size_t)trow * DD + k0 + lq*4);
        float4 wv = *(const float4*)(Wo + (size_t)(n0 + lrow) * DD + k0 + lq*4);
        __syncthreads();
        Hs[lq*4+0][lrow] = hv.x; Hs[lq*4+1][lrow] = hv.y;
        Hs[lq*4+2][lrow] = hv.z; Hs[lq*4+3][lrow] = hv.w;
        Ns[lq*4+0][lrow] = wv.x; Ns[lq*4+1][lrow] = wv.y;
        Ns[lq*4+2][lrow] = wv.z; Ns[lq*4+3][lrow] = wv.w;
        __syncthreads();
        #pragma unroll
        for (int k = 0; k < 16; ++k) {
            float4 a4 = *(const float4*)(&Hs[k][ty*4]);
            float4 c4 = *(const float4*)(&Ns[k][tx*4]);
            float a[4] = {a4.x, a4.y, a4.z, a4.w};
            float c[4] = {c4.x, c4.y, c4.z, c4.w};
            #pragma unroll
            for (int i = 0; i < 4; ++i)
                #pragma unroll
                for (int j = 0; j < 4; ++j)
                    acc[i][j] = fmaf(a[i], c[j], acc[i][j]);
        }
        __syncthreads();
    }

    #pragma unroll
    for (int i = 0; i < 4; ++i) {
        const int t = t0 + ty*4 + i;
        if (t < TT) {
            float4 v;
            v.x = acc[i][0] + bo[n0 + tx*4 + 0];
            v.y = acc[i][1] + bo[n0 + tx*4 + 1];
            v.z = acc[i][2] + bo[n0 + tx*4 + 2];
            v.w = acc[i][3] + bo[n0 + tx*4 + 3];
            *(float4*)(out + ((size_t)b * TT + t) * DD + n0 + tx*4) = v;
        }
    }
}

// ---------------------------------------------------------------------------
extern "C" void kernel_launch(void* const* d_in, const int* in_sizes, int n_in,
                              void* d_out, int out_size, void* d_ws, size_t ws_size,
                              hipStream_t stream)
{
    (void)in_sizes; (void)n_in; (void)out_size; (void)ws_size;

    const float* X    = (const float*)d_in[0];
    const float* Wq   = (const float*)d_in[1];
    const float* bq   = (const float*)d_in[2];
    const float* Wk   = (const float*)d_in[3];
    const float* bk   = (const float*)d_in[4];
    const float* Wv   = (const float*)d_in[5];
    const float* bv   = (const float*)d_in[6];
    const float* Wo   = (const float*)d_in[7];
    const float* bo   = (const float*)d_in[8];
    const float* P    = (const float*)d_in[9];
    const float* orth = (const float*)d_in[10];
    float* out = (float*)d_out;

    // Workspace layout (~46.3 MB):
    //   Qb/Kb/Vb bf16 [B*D*T]        3 x 3,385,344 B
    //   Mtb      bf16 [BE*64*TPAD]       3,407,872 B
    //   Pbf      bf16 [T*TPAD]           5,501,184 B
    //   Mpart    fp32 [4][BE*64][TPAD]  27,262,976 B  (dead after mreduce)
    //   Hbuf     fp32 [B*T*D] -- ALIASES Mpart (written by attn after mreduce)
    char* ws = (char*)d_ws;
    const size_t SZH = (size_t)BB * DD * TT * sizeof(short);
    short* Qb  = (short*)(ws);
    short* Kb  = (short*)(ws + SZH);
    short* Vb  = (short*)(ws + 2 * SZH);
    short* Mtb = (short*)(ws + 3 * SZH);
    short* Pbf = (short*)(ws + 3 * SZH + (size_t)BEH * DE * TPAD * sizeof(short));
    char*  after_p = ws + 3 * SZH + (size_t)BEH * DE * TPAD * sizeof(short)
                        + (size_t)TT * TPAD * sizeof(short);
    float* Mpart = (float*)after_p;
    float* Hbuf  = (float*)after_p;   // alias: Mpart dead before attn runs

    dim3 blk(256);

    convp2_kernel<<<dim3((TT * (TPAD / 4) + 255) / 256), blk, 0, stream>>>(P, Pbf);

    dim3 g1(TTILES, DD / 64, BB * 3);
    proj4_kernel<<<g1, blk, 0, stream>>>(X, Wq, bq, Wk, bk, Wv, bv, Qb, Kb, Vb);

    dim3 g2(SQN, BEH, NJC);
    ovt6_kernel<<<g2, blk, 0, stream>>>(orth, Vb, Mpart);

    dim3 gr((BEH * DE * (TPAD / 4) + 255) / 256);
    mreduce_kernel<<<gr, blk, 0, stream>>>(Mpart, Mtb);

    dim3 g3(TTILES, BEH);
    attn4_kernel<<<g3, blk, 0, stream>>>(Qb, Kb, Mtb, Pbf, Hbuf);

    dim3 g4(TTILES, DD / 64, BB);
    oproj_kernel<<<g4, blk, 0, stream>>>(Hbuf, Wo, bo, out);
}